// Round 1
// baseline (352.004 us; speedup 1.0000x reference)
//
#include <hip/hip_runtime.h>
#include <hip/hip_bf16.h>

// LIF neuron group: 16384 neurons, 2048 sequential steps (batch axis is a
// nonlinear scan carried per-neuron). Parallelism = 1 thread per neuron
// (16384 threads = 256 waves = 1 wave/CU). Memory-bound: 384 MB streamed.
//
// Exactness: output is binary spikes -> must match reference FP op-for-op.
// fp contract(off) + literal op order from the reference:
//   V  = (V + 0.05f*(I - V)) + noise         (each op rounded, no fma)
//   s  = V >= Vth; V = s ? 0 : V
//   Vth = s ? min(max(Vth + 0.1f, 0.5f), 2.0f) : Vth

constexpr int N = 16384;   // neurons
constexpr int T = 2048;    // batch steps (sequential)
constexpr int U = 16;      // time-unroll / prefetch chunk

__global__ __launch_bounds__(64, 1)
void TorchLIFNeuronGroup_85152021610615_kernel(const float* __restrict__ I,
                                               const float* __restrict__ Z,
                                               float* __restrict__ O) {
    #pragma clang fp contract(off)
    const int n = blockIdx.x * 64 + threadIdx.x;
    const float* ip = I + n;
    const float* zp = Z + n;
    float* op = O + n;

    float V   = 0.0f;   // V_RESET
    float Vth = 1.0f;   // V_TH0

    // register double-buffer: chunk currently being computed (bi/bz) and the
    // next chunk in flight (ci/cz). ~8KB/wave outstanding at U=16.
    float bi[U], bz[U];
    #pragma unroll
    for (int u = 0; u < U; ++u) {
        bi[u] = __builtin_nontemporal_load(ip + u * N);
        bz[u] = __builtin_nontemporal_load(zp + u * N);
    }

    for (int t0 = 0; t0 < T; t0 += U) {
        float ci[U], cz[U];
        const bool more = (t0 + U) < T;
        if (more) {
            #pragma unroll
            for (int u = 0; u < U; ++u) {
                ci[u] = __builtin_nontemporal_load(ip + (t0 + U + u) * N);
                cz[u] = __builtin_nontemporal_load(zp + (t0 + U + u) * N);
            }
        }

        #pragma unroll
        for (int u = 0; u < U; ++u) {
            float d  = bi[u] - V;
            float v1 = V + 0.05f * d;     // DT/TAU = 0.05f
            float v2 = v1 + bz[u];
            bool  s  = (v2 >= Vth);
            V = s ? 0.0f : v2;
            float nth = fminf(fmaxf(Vth + 0.1f, 0.5f), 2.0f);  // ETA, MIN_TH, MAX_TH
            Vth = s ? nth : Vth;
            __builtin_nontemporal_store(s ? 1.0f : 0.0f, op + (t0 + u) * N);
        }

        if (more) {
            #pragma unroll
            for (int u = 0; u < U; ++u) { bi[u] = ci[u]; bz[u] = cz[u]; }
        }
    }
}

extern "C" void kernel_launch(void* const* d_in, const int* in_sizes, int n_in,
                              void* d_out, int out_size, void* d_ws, size_t ws_size,
                              hipStream_t stream) {
    const float* input_current = (const float*)d_in[0];
    const float* noise         = (const float*)d_in[1];
    float* out                 = (float*)d_out;

    // 16384 threads: block=64 (1 wave), grid=256 -> 1 wave per CU.
    TorchLIFNeuronGroup_85152021610615_kernel<<<N / 64, 64, 0, stream>>>(
        input_current, noise, out);
}

// Round 2
// 345.658 us; speedup vs baseline: 1.0184x; 1.0184x over previous
//
#include <hip/hip_runtime.h>

// LIF neuron scan: 16384 neurons x 2048 sequential steps. 1 thread/neuron,
// 256 waves = 1 wave/CU (structural). Memory-latency-bound at R1 (2 TB/s,
// ~12 loads in flight/wave). Fix: D-deep register ring pipeline, no copies,
// sched_barrier(0) fences to stop the compiler sinking the prefetch loads.
//
// Exactness: output is binary spikes -> replicate reference FP op-for-op,
// contract(off):  V = (V + 0.05f*(I-V)) + nz ; s = V>=Vth ; V = s?0:V ;
//                 Vth = s ? min(max(Vth+0.1f,0.5f),2.0f) : Vth

constexpr int N = 16384;   // neurons
constexpr int T = 2048;    // sequential steps
constexpr int U = 8;       // steps per chunk
constexpr int D = 8;       // ring depth; (T/U) % D == 0
constexpr int C = T / U;   // 256 chunks

__global__ __launch_bounds__(64, 1)
void TorchLIFNeuronGroup_85152021610615_kernel(const float* __restrict__ I,
                                               const float* __restrict__ Z,
                                               float* __restrict__ O) {
    #pragma clang fp contract(off)
    const int n = blockIdx.x * 64 + threadIdx.x;
    const float* ip = I + n;
    const float* zp = Z + n;
    float* op = O + n;

    float V   = 0.0f;   // V_RESET
    float Vth = 1.0f;   // V_TH0

    // Register ring: D chunks x U steps x 2 streams = 128 VGPRs payload.
    float bi[D][U], bz[D][U];

    // Prologue: issue chunks 0..D-2 into slots 0..D-2 (HW caps 63 outstanding
    // VMEM/wave -> issue stalls harmlessly once saturated).
    #pragma unroll
    for (int d = 0; d < D - 1; ++d) {
        #pragma unroll
        for (int u = 0; u < U; ++u) {
            bi[d][u] = __builtin_nontemporal_load(ip + (size_t)(d * U + u) * N);
            bz[d][u] = __builtin_nontemporal_load(zp + (size_t)(d * U + u) * N);
        }
    }

    for (int sc = 0; sc < C; sc += D) {
        #pragma unroll
        for (int d = 0; d < D; ++d) {
            const int chunk = sc + d;          // chunk being computed this stage
            const int pre   = chunk + (D - 1); // chunk being prefetched
            if (pre < C) {
                const int slot = (d + D - 1) % D;  // slot freed last stage
                #pragma unroll
                for (int u = 0; u < U; ++u) {
                    bi[slot][u] = __builtin_nontemporal_load(ip + (size_t)(pre * U + u) * N);
                    bz[slot][u] = __builtin_nontemporal_load(zp + (size_t)(pre * U + u) * N);
                }
            }
            // Fence: prefetch issue must not sink below the compute block.
            __builtin_amdgcn_sched_barrier(0);

            #pragma unroll
            for (int u = 0; u < U; ++u) {
                float dd = bi[d][u] - V;
                float v1 = V + 0.05f * dd;          // DT/TAU
                float v2 = v1 + bz[d][u];
                bool  s  = (v2 >= Vth);
                V = s ? 0.0f : v2;
                float nth = fminf(fmaxf(Vth + 0.1f, 0.5f), 2.0f);
                Vth = s ? nth : Vth;
                __builtin_nontemporal_store(s ? 1.0f : 0.0f,
                                            op + (size_t)(chunk * U + u) * N);
            }
            __builtin_amdgcn_sched_barrier(0);
        }
    }
}

extern "C" void kernel_launch(void* const* d_in, const int* in_sizes, int n_in,
                              void* d_out, int out_size, void* d_ws, size_t ws_size,
                              hipStream_t stream) {
    const float* input_current = (const float*)d_in[0];
    const float* noise         = (const float*)d_in[1];
    float* out                 = (float*)d_out;

    TorchLIFNeuronGroup_85152021610615_kernel<<<N / 64, 64, 0, stream>>>(
        input_current, noise, out);
}

// Round 3
// 323.814 us; speedup vs baseline: 1.0871x; 1.0675x over previous
//
#include <hip/hip_runtime.h>

// LIF neuron scan: 16384 neurons x 2048 sequential steps, 1 thread/neuron,
// 256 waves = 1 wave/CU (structural). Latency-bound: need ~60 dword loads in
// flight per wave (Little's law: 12KB/wave @ ~365ns, 6.3TB/s target).
//
// R2 failure: conditional prefetch let the scheduler collapse the ring
// (VGPR=72, ~3 chunks live, 488ns serial latency per chunk). R3: steady-state
// loop with UNCONDITIONAL prefetch; stage = {compute slot d, reload slot d
// with chunk+D} -- the register WAR dep pins load placement; epilogue peeled.
//
// Exactness (binary spike output): contract(off), reference op order:
//   V = (V + 0.05f*(I-V)) + nz ; s = V>=Vth ; V = s?0:V ;
//   Vth = s ? min(max(Vth+0.1f,0.5f),2.0f) : Vth

constexpr int N = 16384;    // neurons
constexpr int T = 2048;     // sequential steps
constexpr int U = 4;        // steps per chunk
constexpr int D = 8;        // ring depth
constexpr int C = T / U;    // 512 chunks
constexpr int MAIN = C - D; // 504 chunks in main loop (63 outer iters)

__global__
__attribute__((amdgpu_flat_work_group_size(64, 64)))
__attribute__((amdgpu_waves_per_eu(1, 1)))
void TorchLIFNeuronGroup_85152021610615_kernel(const float* __restrict__ I,
                                               const float* __restrict__ Z,
                                               float* __restrict__ O) {
    #pragma clang fp contract(off)
    const int n = blockIdx.x * 64 + threadIdx.x;
    const float* ip = I + n;
    const float* zp = Z + n;
    float* op = O + n;

    float V   = 0.0f;   // V_RESET
    float Vth = 1.0f;   // V_TH0

    // Register ring: D slots x U steps x 2 streams = 64 floats payload,
    // all live across the outer-loop backedge.
    float bi[D][U], bz[D][U];

    // Prologue: fill all D slots (chunks 0..D-1).
    #pragma unroll
    for (int d = 0; d < D; ++d) {
        #pragma unroll
        for (int u = 0; u < U; ++u) {
            bi[d][u] = __builtin_nontemporal_load(ip + (size_t)(d * U + u) * N);
            bz[d][u] = __builtin_nontemporal_load(zp + (size_t)(d * U + u) * N);
        }
    }

    int t = 0;  // timestep of the chunk being computed
    for (int sc = 0; sc < MAIN; sc += D) {
        #pragma unroll
        for (int d = 0; d < D; ++d) {
            // ---- compute chunk (sc+d) from slot d: timesteps t..t+U-1 ----
            #pragma unroll
            for (int u = 0; u < U; ++u) {
                float dd = bi[d][u] - V;
                float v1 = V + 0.05f * dd;          // DT/TAU
                float v2 = v1 + bz[d][u];
                bool  s  = (v2 >= Vth);
                V = s ? 0.0f : v2;
                float nth = fminf(fmaxf(Vth + 0.1f, 0.5f), 2.0f);
                Vth = s ? nth : Vth;
                __builtin_nontemporal_store(s ? 1.0f : 0.0f,
                                            op + (size_t)(t + u) * N);
            }
            // ---- unconditional prefetch: chunk (sc+d+D) -> slot d ----
            // WAR on bi/bz[d] forces these after the compute block; they are
            // consumed D stages later (next outer iteration, stage d).
            #pragma unroll
            for (int u = 0; u < U; ++u) {
                bi[d][u] = __builtin_nontemporal_load(ip + (size_t)(t + D * U + u) * N);
                bz[d][u] = __builtin_nontemporal_load(zp + (size_t)(t + D * U + u) * N);
            }
            __builtin_amdgcn_sched_barrier(0);
            t += U;
        }
    }

    // Epilogue: last D chunks, no prefetch.
    #pragma unroll
    for (int d = 0; d < D; ++d) {
        #pragma unroll
        for (int u = 0; u < U; ++u) {
            float dd = bi[d][u] - V;
            float v1 = V + 0.05f * dd;
            float v2 = v1 + bz[d][u];
            bool  s  = (v2 >= Vth);
            V = s ? 0.0f : v2;
            float nth = fminf(fmaxf(Vth + 0.1f, 0.5f), 2.0f);
            Vth = s ? nth : Vth;
            __builtin_nontemporal_store(s ? 1.0f : 0.0f,
                                        op + (size_t)(t + u) * N);
        }
        t += U;
    }
}

extern "C" void kernel_launch(void* const* d_in, const int* in_sizes, int n_in,
                              void* d_out, int out_size, void* d_ws, size_t ws_size,
                              hipStream_t stream) {
    const float* input_current = (const float*)d_in[0];
    const float* noise         = (const float*)d_in[1];
    float* out                 = (float*)d_out;

    TorchLIFNeuronGroup_85152021610615_kernel<<<N / 64, 64, 0, stream>>>(
        input_current, noise, out);
}